// Round 1
// baseline (111.948 us; speedup 1.0000x reference)
//
#include <hip/hip_runtime.h>
#include <stdint.h>

#define T1c 128
#define T2c 512
#define TPc 8
#define Hc  16
#define Kc  4
#define Cc  129
#define Dc  256

// ---------- workspace layout (float offsets) ----------
// inv1:   0       (128)
// inv2:   128     (512)
// flag:   640     (1 int)
// e2t:    768     (256*512 = 131072)   e2t[d][t2] = emb_T2[t2][d]
// valv:   131840  (128*512 = 65536)
// mf:     197376  (128*512 = 65536)
// pp:     262912  (8*512 = 4096 ints)  pp[p][t2] = |pos| | sign<<31
// mbase:  267008  (128*8*512 = 524288) mbase[t1][p][t2] = m * base
// total ~791296 floats ~= 3.02 MB

__device__ __forceinline__ int pack_loc(int v) {
    int a = v < 0 ? -v : v;
    return a | (v < 0 ? (int)0x80000000 : 0);
}

// distance core: given packed v1, packed v2 -> (signed d, unsigned magnitude val)
__device__ __forceinline__ void dist_core(unsigned v1, unsigned v2, float& dd, float& val) {
    unsigned xv = v1 ^ v2;
    unsigned xr = xv & 0x7FFFFFFFu;
    // e = 32 - clz(xr+1);  1 - e/16 = clz/16 - 1
    val = fmaf((float)__clz((int)(xr + 1u)), 0.0625f, -1.0f);
    dd  = __uint_as_float(__float_as_uint(val) ^ (xv & 0x80000000u));
}

// K1: row inverse norms for emb_T1 (128) and emb_T2 (512); block 640 detects mask format
__global__ void k_norms(const float* __restrict__ e1, const float* __restrict__ e2,
                        const unsigned char* __restrict__ mask_bytes,
                        float* __restrict__ inv1, float* __restrict__ inv2,
                        int* __restrict__ flag) {
    int b = blockIdx.x;
    int lane = threadIdx.x;  // 64
    if (b < T1c + T2c) {
        const float* src = (b < T1c) ? (e1 + (size_t)b * Dc) : (e2 + (size_t)(b - T1c) * Dc);
        float4 v = ((const float4*)src)[lane];  // 64 lanes * 4 floats = 256
        float s = v.x * v.x + v.y * v.y + v.z * v.z + v.w * v.w;
        #pragma unroll
        for (int off = 32; off; off >>= 1) s += __shfl_xor(s, off, 64);
        if (lane == 0) {
            float r = 1.0f / sqrtf(s);
            if (b < T1c) inv1[b] = r; else inv2[b - T1c] = r;
        }
    } else {
        // mask format detection: if elements are 4-byte (int32/float32 with values 0/1),
        // bytes at offset 1 (mod 4) are always 0. If 1-byte bool, ~80% are 1.
        int nz = 0;
        for (int i = lane; i < 1024; i += 64) nz |= (mask_bytes[1 + 4 * i] != 0) ? 1 : 0;
        unsigned long long any = __ballot(nz);
        if (lane == 0) *flag = (any != 0ULL) ? 1 : 0;
    }
}

// K2: transpose emb_T2 -> e2t[d][t2], and pack pos -> pp[p][t2]
__global__ void k_prep(const float* __restrict__ e2, const int* __restrict__ pos,
                       float* __restrict__ e2t, int* __restrict__ pp) {
    int o = blockIdx.x * 256 + threadIdx.x;
    if (blockIdx.x < 512) {
        int d = o >> 9, t2 = o & 511;
        e2t[o] = e2[(size_t)t2 * Dc + d];
    } else {
        int j = o - 512 * 256;  // [0, 4096)
        int p = j >> 9, t2 = j & 511;
        pp[j] = pack_loc(pos[t2 * TPc + p]);
    }
}

// K3: val_v[t1][t2] = normalized dot; mf[t1][t2] = mask as float (nonzero -> 1)
__global__ void k_valv(const float* __restrict__ e1, const float* __restrict__ e2t,
                       const float* __restrict__ inv1, const float* __restrict__ inv2,
                       const void* __restrict__ mask, const int* __restrict__ flag,
                       float* __restrict__ valv, float* __restrict__ mf) {
    __shared__ float row[Dc];
    int t1 = blockIdx.x >> 1;
    int half = blockIdx.x & 1;
    int tid = threadIdx.x;  // 256
    row[tid] = e1[(size_t)t1 * Dc + tid];
    __syncthreads();
    int t2 = half * 256 + tid;
    float a0 = 0.f, a1 = 0.f, a2 = 0.f, a3 = 0.f;
    #pragma unroll 4
    for (int d = 0; d < Dc; d += 4) {
        a0 = fmaf(row[d + 0], e2t[(size_t)(d + 0) * T2c + t2], a0);
        a1 = fmaf(row[d + 1], e2t[(size_t)(d + 1) * T2c + t2], a1);
        a2 = fmaf(row[d + 2], e2t[(size_t)(d + 2) * T2c + t2], a2);
        a3 = fmaf(row[d + 3], e2t[(size_t)(d + 3) * T2c + t2], a3);
    }
    float acc = (a0 + a1) + (a2 + a3);
    int idx = t1 * T2c + t2;
    valv[idx] = acc * inv1[t1] * inv2[t2];
    float m;
    if (*flag) m = (((const unsigned char*)mask)[idx] != 0) ? 1.0f : 0.0f;
    else       m = (((const int*)mask)[idx] != 0) ? 1.0f : 0.0f;
    mf[idx] = m;
}

// K4: mbase[t1][p][t2] = m*((dsum - dis_sta[p])/8 - val_v);  out[t1][64][p] = sum m*(dsum/8 - vv)^2
__global__ void k_base(const int* __restrict__ sta, const int* __restrict__ pp,
                       const float* __restrict__ valv, const float* __restrict__ mf,
                       float* __restrict__ mbase, float* __restrict__ out) {
    int t1 = blockIdx.x >> 1;
    int half = blockIdx.x & 1;
    int tid = threadIdx.x;  // 256
    __shared__ int s1p[TPc];
    __shared__ float red[4];
    if (tid < TPc) s1p[tid] = pack_loc(sta[t1 * TPc + tid]);
    __syncthreads();
    int t2 = half * 256 + tid;
    float vv = valv[t1 * T2c + t2];
    float m  = mf[t1 * T2c + t2];
    float d[TPc];
    float dsum = 0.f;
    #pragma unroll
    for (int p = 0; p < TPc; ++p) {
        float dd, val;
        dist_core((unsigned)s1p[p], (unsigned)pp[p * T2c + t2], dd, val);
        d[p] = dd;
        dsum += dd;
    }
    float c64 = dsum * 0.125f - vv;
    float s64 = m * c64 * c64;
    #pragma unroll
    for (int p = 0; p < TPc; ++p) {
        float base = (dsum - d[p]) * 0.125f - vv;
        mbase[((size_t)t1 * TPc + p) * T2c + t2] = m * base;
    }
    // block-reduce s64 (256 threads = 4 waves)
    #pragma unroll
    for (int off = 32; off; off >>= 1) s64 += __shfl_xor(s64, off, 64);
    int wave = tid >> 6;
    if ((tid & 63) == 0) red[wave] = s64;
    __syncthreads();
    if (tid < TPc) {
        float tot = (red[0] + red[1]) + (red[2] + red[3]);
        atomicAdd(&out[((size_t)t1 * Cc + 64) * TPc + tid], tot);
    }
}

// K5: main loop. grid = t1(128) x cg(2) x t2h(4); block 256: thread = (c = cg*32 + tid>>3, p = tid&7)
// computes A = sum m*base^2, B = sum (m*base)*d, Q = sum m*d^2 over a 128-wide t2 slice;
// loss[c]    += A + B/4 + Q/64
// loss[65+c] += A - B/4 + Q/64   (or +B/4 if res==0, since -0 keeps sign convention)
__global__ __launch_bounds__(256) void k_main(const int* __restrict__ sta,
                                              const int* __restrict__ rm,
                                              const int* __restrict__ pp,
                                              const float* __restrict__ mbase,
                                              const float* __restrict__ mf,
                                              float* __restrict__ out) {
    int b = blockIdx.x;
    int t2h = b & 3;
    int cg  = (b >> 2) & 1;
    int t1  = b >> 3;
    int tid = threadIdx.x;
    int p = tid & 7;
    int c = cg * 32 + (tid >> 3);   // [0, 64)
    int i = c >> 2, k = c & 3;
    int stav = sta[t1 * TPc + p];
    int low  = rm[(((t1 * Hc + i) * Kc + k) * TPc) + p] & ((1 << i) - 1);
    int resv = (stav ^ (1 << i)) ^ low;
    unsigned v1 = (unsigned)pack_loc(resv);

    const int4*   pp4 = (const int4*)(pp + p * T2c + t2h * 128);
    const float4* mb4 = (const float4*)(mbase + ((size_t)t1 * TPc + p) * T2c + t2h * 128);
    const float4* mf4 = (const float4*)(mf + (size_t)t1 * T2c + t2h * 128);

    float A = 0.f, B = 0.f, Q = 0.f;
    #pragma unroll 4
    for (int j = 0; j < 32; ++j) {
        int4   pv = pp4[j];
        float4 mb = mb4[j];
        float4 mm = mf4[j];
        float dd, val;
        dist_core(v1, (unsigned)pv.x, dd, val);
        B = fmaf(mb.x, dd, B); Q = fmaf(mm.x * val, val, Q); A = fmaf(mb.x, mb.x, A);
        dist_core(v1, (unsigned)pv.y, dd, val);
        B = fmaf(mb.y, dd, B); Q = fmaf(mm.y * val, val, Q); A = fmaf(mb.y, mb.y, A);
        dist_core(v1, (unsigned)pv.z, dd, val);
        B = fmaf(mb.z, dd, B); Q = fmaf(mm.z * val, val, Q); A = fmaf(mb.z, mb.z, A);
        dist_core(v1, (unsigned)pv.w, dd, val);
        B = fmaf(mb.w, dd, B); Q = fmaf(mm.w * val, val, Q); A = fmaf(mb.w, mb.w, A);
    }
    float core = A + Q * (1.0f / 64.0f);
    float l0 = core + B * 0.25f;
    float l1 = (resv == 0) ? l0 : (core - B * 0.25f);
    atomicAdd(&out[((size_t)t1 * Cc + c) * TPc + p], l0);
    atomicAdd(&out[((size_t)t1 * Cc + 65 + c) * TPc + p], l1);
}

extern "C" void kernel_launch(void* const* d_in, const int* in_sizes, int n_in,
                              void* d_out, int out_size, void* d_ws, size_t ws_size,
                              hipStream_t stream) {
    const float* emb1 = (const float*)d_in[0];
    const float* emb2 = (const float*)d_in[1];
    const int*   sta  = (const int*)d_in[2];
    const int*   pos  = (const int*)d_in[3];
    const void*  mask = d_in[4];
    const int*   rm   = (const int*)d_in[5];
    float* out = (float*)d_out;

    float* ws    = (float*)d_ws;
    float* inv1  = ws;
    float* inv2  = ws + 128;
    int*   flag  = (int*)(ws + 640);
    float* e2t   = ws + 768;
    float* valv  = ws + 131840;
    float* mfv   = ws + 197376;
    int*   pp    = (int*)(ws + 262912);
    float* mbase = ws + 267008;

    hipMemsetAsync(d_out, 0, (size_t)T1c * Cc * TPc * sizeof(float), stream);
    hipLaunchKernelGGL(k_norms, dim3(T1c + T2c + 1), dim3(64), 0, stream,
                       emb1, emb2, (const unsigned char*)mask, inv1, inv2, flag);
    hipLaunchKernelGGL(k_prep, dim3(528), dim3(256), 0, stream, emb2, pos, e2t, pp);
    hipLaunchKernelGGL(k_valv, dim3(256), dim3(256), 0, stream,
                       emb1, e2t, inv1, inv2, mask, flag, valv, mfv);
    hipLaunchKernelGGL(k_base, dim3(256), dim3(256), 0, stream,
                       sta, pp, valv, mfv, mbase, out);
    hipLaunchKernelGGL(k_main, dim3(1024), dim3(256), 0, stream,
                       sta, rm, pp, mbase, mfv, out);
}